// Round 1
// baseline (665.314 us; speedup 1.0000x reference)
//
#include <hip/hip_runtime.h>
#include <hip/hip_bf16.h>
#include <math.h>

// ---------------------------------------------------------------------------
// GCN: 3x gcn_conv(relu) -> tri-pool per graph -> MLP head -> sigmoid
// All fp32. Aggregation via CSR (sorted by dst) built on-device each call.
// ---------------------------------------------------------------------------

__global__ void count_kernel(const int* __restrict__ idx, int* __restrict__ cnt, int n) {
    int i = blockIdx.x * blockDim.x + threadIdx.x;
    if (i < n) atomicAdd(&cnt[idx[i]], 1);
}

__global__ void dinv_kernel(const int* __restrict__ deg, float* __restrict__ dv, int n) {
    int i = blockIdx.x * blockDim.x + threadIdx.x;
    if (i < n) dv[i] = 1.0f / sqrtf((float)deg[i] + 1.0f);
}

__device__ inline int wave_incl_scan(int v, int lane) {
    #pragma unroll
    for (int off = 1; off < 64; off <<= 1) {
        int nv = __shfl_up(v, off, 64);
        if (lane >= off) v += nv;
    }
    return v;
}

// Single-block exclusive scan of n ints; writes out[0..n] (out[n]=total).
// Optionally duplicates result into out2 (cursor copy for CSR fill).
__global__ void scan_excl(const int* __restrict__ in, int n,
                          int* __restrict__ out, int* __restrict__ out2) {
    __shared__ int wsum[16];
    __shared__ int carry_s;
    const int t = threadIdx.x;
    const int lane = t & 63;
    const int wid = t >> 6;
    if (t == 0) carry_s = 0;
    __syncthreads();
    const int CH = 4096;  // 1024 threads * 4 elems
    for (int base = 0; base < n; base += CH) {
        int i0 = base + t * 4;
        int v[4];
        #pragma unroll
        for (int j = 0; j < 4; ++j) v[j] = (i0 + j < n) ? in[i0 + j] : 0;
        int local = v[0] + v[1] + v[2] + v[3];
        int isc = wave_incl_scan(local, lane);
        if (lane == 63) wsum[wid] = isc;
        __syncthreads();
        int carry = carry_s;
        int wbase = 0;
        for (int w = 0; w < wid; ++w) wbase += wsum[w];
        int total = 0;
        for (int w = 0; w < 16; ++w) total += wsum[w];
        int run = carry + wbase + isc - local;  // exclusive prefix for v[0]
        #pragma unroll
        for (int j = 0; j < 4; ++j) {
            int i = i0 + j;
            if (i < n) {
                out[i] = run;
                if (out2) out2[i] = run;
            }
            run += v[j];
        }
        __syncthreads();
        if (t == 0) carry_s = carry + total;
        __syncthreads();
    }
    if (t == 0) out[n] = carry_s;
}

__global__ void fill_csr(const int* __restrict__ src, const int* __restrict__ dst,
                         int* __restrict__ cursor, int* __restrict__ colsrc, int E) {
    int e = blockIdx.x * blockDim.x + threadIdx.x;
    if (e < E) {
        int p = atomicAdd(&cursor[dst[e]], 1);
        colsrc[p] = src[e];
    }
}

// out[row][:] = (X[row][:] @ W) * dinv[row]      (X: Mx128, W: 128x128 row-major)
__global__ __launch_bounds__(256) void gemm_scale(
    const float* __restrict__ X, const float* __restrict__ W,
    const float* __restrict__ dv, float* __restrict__ out, int M) {
    __shared__ float wlds[128 * 128];
    for (int i = threadIdx.x; i < 128 * 128 / 4; i += 256)
        ((float4*)wlds)[i] = ((const float4*)W)[i];
    __syncthreads();

    const int tx = threadIdx.x & 15;   // 16 col groups of 8 -> 128 cols
    const int ty = threadIdx.x >> 4;   // 16 row groups of 4 -> 64 rows
    const int row0 = blockIdx.x * 64 + ty * 4;

    float acc[4][8];
    #pragma unroll
    for (int r = 0; r < 4; ++r)
        #pragma unroll
        for (int c = 0; c < 8; ++c) acc[r][c] = 0.0f;

    for (int k0 = 0; k0 < 128; k0 += 8) {
        float xa[4][8];
        #pragma unroll
        for (int r = 0; r < 4; ++r) {
            if (row0 + r < M) {
                const float* xp = X + (size_t)(row0 + r) * 128 + k0;
                float4 a = *(const float4*)xp;
                float4 b = *(const float4*)(xp + 4);
                xa[r][0] = a.x; xa[r][1] = a.y; xa[r][2] = a.z; xa[r][3] = a.w;
                xa[r][4] = b.x; xa[r][5] = b.y; xa[r][6] = b.z; xa[r][7] = b.w;
            } else {
                #pragma unroll
                for (int j = 0; j < 8; ++j) xa[r][j] = 0.0f;
            }
        }
        #pragma unroll
        for (int kk = 0; kk < 8; ++kk) {
            const float* wr = &wlds[(k0 + kk) * 128 + tx * 8];
            float4 w0 = *(const float4*)wr;
            float4 w1 = *(const float4*)(wr + 4);
            #pragma unroll
            for (int r = 0; r < 4; ++r) {
                float xv = xa[r][kk];
                acc[r][0] += xv * w0.x; acc[r][1] += xv * w0.y;
                acc[r][2] += xv * w0.z; acc[r][3] += xv * w0.w;
                acc[r][4] += xv * w1.x; acc[r][5] += xv * w1.y;
                acc[r][6] += xv * w1.z; acc[r][7] += xv * w1.w;
            }
        }
    }

    #pragma unroll
    for (int r = 0; r < 4; ++r) {
        int row = row0 + r;
        if (row < M) {
            float d = dv[row];
            float4 o0 = make_float4(acc[r][0] * d, acc[r][1] * d, acc[r][2] * d, acc[r][3] * d);
            float4 o1 = make_float4(acc[r][4] * d, acc[r][5] * d, acc[r][6] * d, acc[r][7] * d);
            float* op = out + (size_t)row * 128 + tx * 8;
            *(float4*)op = o0;
            *(float4*)(op + 4) = o1;
        }
    }
}

// One wave per node v:
//   out[v] = relu(b + dinv[v] * (hs[v] + sum_{e: dst=v} hs[src[e]]))
// where hs = (x@W)*dinv (pre-scaled rows).
__global__ __launch_bounds__(256) void agg_relu(
    const float* __restrict__ hs, const float* __restrict__ dv,
    const float* __restrict__ bias, const int* __restrict__ rowoff,
    const int* __restrict__ colsrc, float* __restrict__ out, int n) {
    const int lane = threadIdx.x & 63;
    const int v = blockIdx.x * 4 + (threadIdx.x >> 6);
    if (v >= n) return;

    const float* hv = hs + (size_t)v * 128 + lane * 2;
    float2 acc = *(const float2*)hv;
    const int e0 = rowoff[v], e1 = rowoff[v + 1];
    for (int e = e0; e < e1; ++e) {
        int s = colsrc[e];
        float2 m = *(const float2*)(hs + (size_t)s * 128 + lane * 2);
        acc.x += m.x;
        acc.y += m.y;
    }
    float d = dv[v];
    float2 bb = *(const float2*)(bias + lane * 2);
    float ox = fmaxf(fmaf(d, acc.x, bb.x), 0.0f);
    float oy = fmaxf(fmaf(d, acc.y, bb.y), 0.0f);
    *(float2*)(out + (size_t)v * 128 + lane * 2) = make_float2(ox, oy);
}

// One block (128 threads) per graph; batch is sorted so graph g owns nodes
// [goff[g], goff[g+1]). gfeat[g] = [pmean(128) | pmax(128) | psum(128)]
__global__ __launch_bounds__(128) void pool_kernel(
    const float* __restrict__ h, const int* __restrict__ goff,
    float* __restrict__ gfeat) {
    const int g = blockIdx.x, f = threadIdx.x;
    const int s = goff[g], e = goff[g + 1];
    float sum = 0.0f, mx = 0.0f;  // h >= 0 post-relu; empty graph -> 0 matches ref
    for (int v = s; v < e; ++v) {
        float val = h[(size_t)v * 128 + f];
        sum += val;
        mx = fmaxf(mx, val);
    }
    float cnt = (float)(e - s);
    float* gp = gfeat + (size_t)g * 384;
    gp[f]       = sum / fmaxf(cnt, 1.0f);
    gp[128 + f] = mx;
    gp[256 + f] = sum;
}

// One block (128 threads) per graph: relu(g@lw1+lb1) -> relu(@lw2+lb2) -> sigmoid(@lw3+lb3)
__global__ __launch_bounds__(128) void mlp_kernel(
    const float* __restrict__ gfeat,
    const float* __restrict__ lw1, const float* __restrict__ lb1,
    const float* __restrict__ lw2, const float* __restrict__ lb2,
    const float* __restrict__ lw3, const float* __restrict__ lb3,
    float* __restrict__ out) {
    __shared__ float gin[384];
    __shared__ float h1[384];
    __shared__ float red[128];
    const int g = blockIdx.x, t = threadIdx.x;

    for (int i = t; i < 384; i += 128) gin[i] = gfeat[(size_t)g * 384 + i];
    __syncthreads();

    for (int j = t; j < 384; j += 128) {
        float acc = lb1[j];
        for (int i = 0; i < 384; ++i) acc = fmaf(gin[i], lw1[(size_t)i * 384 + j], acc);
        h1[j] = fmaxf(acc, 0.0f);
    }
    __syncthreads();

    float acc2 = lb2[t];
    for (int i = 0; i < 384; ++i) acc2 = fmaf(h1[i], lw2[(size_t)i * 128 + t], acc2);
    float h2 = fmaxf(acc2, 0.0f);

    red[t] = h2 * lw3[t];
    __syncthreads();
    for (int s = 64; s > 0; s >>= 1) {
        if (t < s) red[t] += red[t + s];
        __syncthreads();
    }
    if (t == 0) {
        float z = red[0] + lb3[0];
        out[g] = 1.0f / (1.0f + expf(-z));
    }
}

extern "C" void kernel_launch(void* const* d_in, const int* in_sizes, int n_in,
                              void* d_out, int out_size, void* d_ws, size_t ws_size,
                              hipStream_t stream) {
    (void)n_in; (void)ws_size;
    const float* x     = (const float*)d_in[0];
    const int*   ei    = (const int*)d_in[1];
    const int*   batch = (const int*)d_in[2];
    const float* W1  = (const float*)d_in[3];
    const float* b1  = (const float*)d_in[4];
    const float* W2  = (const float*)d_in[5];
    const float* b2  = (const float*)d_in[6];
    const float* lw1 = (const float*)d_in[7];
    const float* lb1 = (const float*)d_in[8];
    const float* lw2 = (const float*)d_in[9];
    const float* lb2 = (const float*)d_in[10];
    const float* lw3 = (const float*)d_in[11];
    const float* lb3 = (const float*)d_in[12];
    float* out = (float*)d_out;

    const int N = in_sizes[2];      // 50000 nodes (batch length)
    const int E = in_sizes[1] / 2;  // 800000 edges
    const int G = out_size;         // 512 graphs

    const int* src = ei;
    const int* dst = ei + E;

    size_t off = 0;
    auto alloc = [&](size_t bytes) -> void* {
        void* p = (char*)d_ws + off;
        off += (bytes + 255) & ~(size_t)255;
        return p;
    };
    float* hA     = (float*)alloc((size_t)N * 128 * 4);
    float* hB     = (float*)alloc((size_t)N * 128 * 4);
    float* dv     = (float*)alloc((size_t)N * 4);
    int*   deg    = (int*)alloc((size_t)N * 4);
    int*   rowoff = (int*)alloc((size_t)(N + 1) * 4);
    int*   cursor = (int*)alloc((size_t)N * 4);
    int*   colsrc = (int*)alloc((size_t)E * 4);
    int*   gcnt   = (int*)alloc((size_t)G * 4);
    int*   goff   = (int*)alloc((size_t)(G + 1) * 4);
    float* gfeat  = (float*)alloc((size_t)G * 384 * 4);

    hipMemsetAsync(deg, 0, (size_t)N * 4, stream);
    hipMemsetAsync(gcnt, 0, (size_t)G * 4, stream);

    const int tb = 256;
    count_kernel<<<(E + tb - 1) / tb, tb, 0, stream>>>(dst, deg, E);
    count_kernel<<<(N + tb - 1) / tb, tb, 0, stream>>>(batch, gcnt, N);
    dinv_kernel<<<(N + tb - 1) / tb, tb, 0, stream>>>(deg, dv, N);
    scan_excl<<<1, 1024, 0, stream>>>(deg, N, rowoff, cursor);
    scan_excl<<<1, 1024, 0, stream>>>(gcnt, G, goff, (int*)nullptr);
    fill_csr<<<(E + tb - 1) / tb, tb, 0, stream>>>(src, dst, cursor, colsrc, E);

    const int gemm_blocks = (N + 63) / 64;
    const int agg_blocks  = (N + 3) / 4;

    // layer 1
    gemm_scale<<<gemm_blocks, 256, 0, stream>>>(x, W1, dv, hA, N);
    agg_relu<<<agg_blocks, 256, 0, stream>>>(hA, dv, b1, rowoff, colsrc, hB, N);
    // layer 2
    gemm_scale<<<gemm_blocks, 256, 0, stream>>>(hB, W2, dv, hA, N);
    agg_relu<<<agg_blocks, 256, 0, stream>>>(hA, dv, b2, rowoff, colsrc, hB, N);
    // layer 3 (shared weights W2/b2)
    gemm_scale<<<gemm_blocks, 256, 0, stream>>>(hB, W2, dv, hA, N);
    agg_relu<<<agg_blocks, 256, 0, stream>>>(hA, dv, b2, rowoff, colsrc, hB, N);

    pool_kernel<<<G, 128, 0, stream>>>(hB, goff, gfeat);
    mlp_kernel<<<G, 128, 0, stream>>>(gfeat, lw1, lb1, lw2, lb2, lw3, lb3, out);
}

// Round 2
// 510.063 us; speedup vs baseline: 1.3044x; 1.3044x over previous
//
#include <hip/hip_runtime.h>
#include <hip/hip_bf16.h>
#include <hip/hip_fp16.h>
#include <math.h>

// ---------------------------------------------------------------------------
// GCN: 3x gcn_conv(relu) -> tri-pool per graph -> MLP head -> sigmoid
// fp32 compute; the gathered intermediate hs = (x@W)*dinv stored fp16 to
// halve gather traffic. Aggregation via CSR (sorted by dst) built per call.
// ---------------------------------------------------------------------------

__global__ void count_kernel(const int* __restrict__ idx, int* __restrict__ cnt, int n) {
    int i = blockIdx.x * blockDim.x + threadIdx.x;
    if (i < n) atomicAdd(&cnt[idx[i]], 1);
}

__global__ void dinv_kernel(const int* __restrict__ deg, float* __restrict__ dv, int n) {
    int i = blockIdx.x * blockDim.x + threadIdx.x;
    if (i < n) dv[i] = 1.0f / sqrtf((float)deg[i] + 1.0f);
}

__device__ inline int wave_incl_scan(int v, int lane) {
    #pragma unroll
    for (int off = 1; off < 64; off <<= 1) {
        int nv = __shfl_up(v, off, 64);
        if (lane >= off) v += nv;
    }
    return v;
}

// Single-block exclusive scan of n ints; writes out[0..n] (out[n]=total).
// Optionally duplicates result into out2 (cursor copy for CSR fill).
__global__ void scan_excl(const int* __restrict__ in, int n,
                          int* __restrict__ out, int* __restrict__ out2) {
    __shared__ int wsum[16];
    __shared__ int carry_s;
    const int t = threadIdx.x;
    const int lane = t & 63;
    const int wid = t >> 6;
    if (t == 0) carry_s = 0;
    __syncthreads();
    const int CH = 4096;  // 1024 threads * 4 elems
    for (int base = 0; base < n; base += CH) {
        int i0 = base + t * 4;
        int v[4];
        #pragma unroll
        for (int j = 0; j < 4; ++j) v[j] = (i0 + j < n) ? in[i0 + j] : 0;
        int local = v[0] + v[1] + v[2] + v[3];
        int isc = wave_incl_scan(local, lane);
        if (lane == 63) wsum[wid] = isc;
        __syncthreads();
        int carry = carry_s;
        int wbase = 0;
        for (int w = 0; w < wid; ++w) wbase += wsum[w];
        int total = 0;
        for (int w = 0; w < 16; ++w) total += wsum[w];
        int run = carry + wbase + isc - local;  // exclusive prefix for v[0]
        #pragma unroll
        for (int j = 0; j < 4; ++j) {
            int i = i0 + j;
            if (i < n) {
                out[i] = run;
                if (out2) out2[i] = run;
            }
            run += v[j];
        }
        __syncthreads();
        if (t == 0) carry_s = carry + total;
        __syncthreads();
    }
    if (t == 0) out[n] = carry_s;
}

__global__ void fill_csr(const int* __restrict__ src, const int* __restrict__ dst,
                         int* __restrict__ cursor, int* __restrict__ colsrc, int E) {
    int e = blockIdx.x * blockDim.x + threadIdx.x;
    if (e < E) {
        int p = atomicAdd(&cursor[dst[e]], 1);
        colsrc[p] = src[e];
    }
}

// out[row][:] = fp16((X[row][:] @ W) * dinv[row])   (X: Mx128 f32, W: 128x128)
__global__ __launch_bounds__(256) void gemm_scale_h(
    const float* __restrict__ X, const float* __restrict__ W,
    const float* __restrict__ dv, __half* __restrict__ outh, int M) {
    __shared__ float wlds[128 * 128];
    for (int i = threadIdx.x; i < 128 * 128 / 4; i += 256)
        ((float4*)wlds)[i] = ((const float4*)W)[i];
    __syncthreads();

    const int tx = threadIdx.x & 15;   // 16 col groups of 8 -> 128 cols
    const int ty = threadIdx.x >> 4;   // 16 row groups of 4 -> 64 rows
    const int row0 = blockIdx.x * 64 + ty * 4;

    float acc[4][8];
    #pragma unroll
    for (int r = 0; r < 4; ++r)
        #pragma unroll
        for (int c = 0; c < 8; ++c) acc[r][c] = 0.0f;

    for (int k0 = 0; k0 < 128; k0 += 8) {
        float xa[4][8];
        #pragma unroll
        for (int r = 0; r < 4; ++r) {
            if (row0 + r < M) {
                const float* xp = X + (size_t)(row0 + r) * 128 + k0;
                float4 a = *(const float4*)xp;
                float4 b = *(const float4*)(xp + 4);
                xa[r][0] = a.x; xa[r][1] = a.y; xa[r][2] = a.z; xa[r][3] = a.w;
                xa[r][4] = b.x; xa[r][5] = b.y; xa[r][6] = b.z; xa[r][7] = b.w;
            } else {
                #pragma unroll
                for (int j = 0; j < 8; ++j) xa[r][j] = 0.0f;
            }
        }
        #pragma unroll
        for (int kk = 0; kk < 8; ++kk) {
            const float* wr = &wlds[(k0 + kk) * 128 + tx * 8];
            float4 w0 = *(const float4*)wr;
            float4 w1 = *(const float4*)(wr + 4);
            #pragma unroll
            for (int r = 0; r < 4; ++r) {
                float xv = xa[r][kk];
                acc[r][0] += xv * w0.x; acc[r][1] += xv * w0.y;
                acc[r][2] += xv * w0.z; acc[r][3] += xv * w0.w;
                acc[r][4] += xv * w1.x; acc[r][5] += xv * w1.y;
                acc[r][6] += xv * w1.z; acc[r][7] += xv * w1.w;
            }
        }
    }

    struct __align__(16) H8 { __half2 a, b, c, d; };
    #pragma unroll
    for (int r = 0; r < 4; ++r) {
        int row = row0 + r;
        if (row < M) {
            float d = dv[row];
            H8 val;
            val.a = __floats2half2_rn(acc[r][0] * d, acc[r][1] * d);
            val.b = __floats2half2_rn(acc[r][2] * d, acc[r][3] * d);
            val.c = __floats2half2_rn(acc[r][4] * d, acc[r][5] * d);
            val.d = __floats2half2_rn(acc[r][6] * d, acc[r][7] * d);
            *(H8*)(outh + (size_t)row * 128 + tx * 8) = val;
        }
    }
}

// One wave per node v; hs rows are 128 fp16 (64 half2 per row, lane owns 2 feats):
//   out[v] = relu(b + dinv[v] * (hs[v] + sum_{e: dst=v} hs[src[e]]))
// Edge indices pre-gathered 64-wide (one coalesced load), broadcast by shfl;
// inner loop unrolled x4 for 4 row-loads in flight.
__global__ __launch_bounds__(256) void agg_relu_h(
    const __half2* __restrict__ hs, const float* __restrict__ dv,
    const float* __restrict__ bias, const int* __restrict__ rowoff,
    const int* __restrict__ colsrc, float* __restrict__ out, int n) {
    const int lane = threadIdx.x & 63;
    const int v = blockIdx.x * 4 + (threadIdx.x >> 6);
    if (v >= n) return;

    float2 acc = __half22float2(hs[(size_t)v * 64 + lane]);  // self term
    const int e0 = rowoff[v], e1 = rowoff[v + 1];
    const int deg = e1 - e0;

    for (int base = 0; base < deg; base += 64) {
        const int cnt = min(64, deg - base);
        int myidx = (base + lane < deg) ? colsrc[e0 + base + lane] : 0;
        int j = 0;
        for (; j + 4 <= cnt; j += 4) {
            int s0 = __shfl(myidx, j);
            int s1 = __shfl(myidx, j + 1);
            int s2 = __shfl(myidx, j + 2);
            int s3 = __shfl(myidx, j + 3);
            __half2 m0 = hs[(size_t)s0 * 64 + lane];
            __half2 m1 = hs[(size_t)s1 * 64 + lane];
            __half2 m2 = hs[(size_t)s2 * 64 + lane];
            __half2 m3 = hs[(size_t)s3 * 64 + lane];
            float2 f0 = __half22float2(m0), f1 = __half22float2(m1);
            float2 f2 = __half22float2(m2), f3 = __half22float2(m3);
            acc.x += (f0.x + f1.x) + (f2.x + f3.x);
            acc.y += (f0.y + f1.y) + (f2.y + f3.y);
        }
        for (; j < cnt; ++j) {
            int s = __shfl(myidx, j);
            float2 f = __half22float2(hs[(size_t)s * 64 + lane]);
            acc.x += f.x;
            acc.y += f.y;
        }
    }

    float d = dv[v];
    float2 bb = *(const float2*)(bias + lane * 2);
    float ox = fmaxf(fmaf(d, acc.x, bb.x), 0.0f);
    float oy = fmaxf(fmaf(d, acc.y, bb.y), 0.0f);
    *(float2*)(out + (size_t)v * 128 + lane * 2) = make_float2(ox, oy);
}

// One block (128 threads) per graph; batch is sorted so graph g owns nodes
// [goff[g], goff[g+1]). gfeat[g] = [pmean(128) | pmax(128) | psum(128)]
__global__ __launch_bounds__(128) void pool_kernel(
    const float* __restrict__ h, const int* __restrict__ goff,
    float* __restrict__ gfeat) {
    const int g = blockIdx.x, f = threadIdx.x;
    const int s = goff[g], e = goff[g + 1];
    float sum = 0.0f, mx = 0.0f;  // h >= 0 post-relu; empty graph -> 0 matches ref
    for (int v = s; v < e; ++v) {
        float val = h[(size_t)v * 128 + f];
        sum += val;
        mx = fmaxf(mx, val);
    }
    float cnt = (float)(e - s);
    float* gp = gfeat + (size_t)g * 384;
    gp[f]       = sum / fmaxf(cnt, 1.0f);
    gp[128 + f] = mx;
    gp[256 + f] = sum;
}

// One block (128 threads) per graph: relu(g@lw1+lb1) -> relu(@lw2+lb2) -> sigmoid(@lw3+lb3)
__global__ __launch_bounds__(128) void mlp_kernel(
    const float* __restrict__ gfeat,
    const float* __restrict__ lw1, const float* __restrict__ lb1,
    const float* __restrict__ lw2, const float* __restrict__ lb2,
    const float* __restrict__ lw3, const float* __restrict__ lb3,
    float* __restrict__ out) {
    __shared__ float gin[384];
    __shared__ float h1[384];
    __shared__ float red[128];
    const int g = blockIdx.x, t = threadIdx.x;

    for (int i = t; i < 384; i += 128) gin[i] = gfeat[(size_t)g * 384 + i];
    __syncthreads();

    for (int j = t; j < 384; j += 128) {
        float acc = lb1[j];
        for (int i = 0; i < 384; ++i) acc = fmaf(gin[i], lw1[(size_t)i * 384 + j], acc);
        h1[j] = fmaxf(acc, 0.0f);
    }
    __syncthreads();

    float acc2 = lb2[t];
    for (int i = 0; i < 384; ++i) acc2 = fmaf(h1[i], lw2[(size_t)i * 128 + t], acc2);
    float h2 = fmaxf(acc2, 0.0f);

    red[t] = h2 * lw3[t];
    __syncthreads();
    for (int s = 64; s > 0; s >>= 1) {
        if (t < s) red[t] += red[t + s];
        __syncthreads();
    }
    if (t == 0) {
        float z = red[0] + lb3[0];
        out[g] = 1.0f / (1.0f + expf(-z));
    }
}

extern "C" void kernel_launch(void* const* d_in, const int* in_sizes, int n_in,
                              void* d_out, int out_size, void* d_ws, size_t ws_size,
                              hipStream_t stream) {
    (void)n_in; (void)ws_size;
    const float* x     = (const float*)d_in[0];
    const int*   ei    = (const int*)d_in[1];
    const int*   batch = (const int*)d_in[2];
    const float* W1  = (const float*)d_in[3];
    const float* b1  = (const float*)d_in[4];
    const float* W2  = (const float*)d_in[5];
    const float* b2  = (const float*)d_in[6];
    const float* lw1 = (const float*)d_in[7];
    const float* lb1 = (const float*)d_in[8];
    const float* lw2 = (const float*)d_in[9];
    const float* lb2 = (const float*)d_in[10];
    const float* lw3 = (const float*)d_in[11];
    const float* lb3 = (const float*)d_in[12];
    float* out = (float*)d_out;

    const int N = in_sizes[2];      // 50000 nodes (batch length)
    const int E = in_sizes[1] / 2;  // 800000 edges
    const int G = out_size;         // 512 graphs

    const int* src = ei;
    const int* dst = ei + E;

    size_t off = 0;
    auto alloc = [&](size_t bytes) -> void* {
        void* p = (char*)d_ws + off;
        off += (bytes + 255) & ~(size_t)255;
        return p;
    };
    __half* hsA   = (__half*)alloc((size_t)N * 128 * 2);   // fp16 gathered intermediate
    float* hB     = (float*)alloc((size_t)N * 128 * 4);
    float* dv     = (float*)alloc((size_t)N * 4);
    int*   deg    = (int*)alloc((size_t)N * 4);
    int*   rowoff = (int*)alloc((size_t)(N + 1) * 4);
    int*   cursor = (int*)alloc((size_t)N * 4);
    int*   colsrc = (int*)alloc((size_t)E * 4);
    int*   gcnt   = (int*)alloc((size_t)G * 4);
    int*   goff   = (int*)alloc((size_t)(G + 1) * 4);
    float* gfeat  = (float*)alloc((size_t)G * 384 * 4);

    hipMemsetAsync(deg, 0, (size_t)N * 4, stream);
    hipMemsetAsync(gcnt, 0, (size_t)G * 4, stream);

    const int tb = 256;
    count_kernel<<<(E + tb - 1) / tb, tb, 0, stream>>>(dst, deg, E);
    count_kernel<<<(N + tb - 1) / tb, tb, 0, stream>>>(batch, gcnt, N);
    dinv_kernel<<<(N + tb - 1) / tb, tb, 0, stream>>>(deg, dv, N);
    scan_excl<<<1, 1024, 0, stream>>>(deg, N, rowoff, cursor);
    scan_excl<<<1, 1024, 0, stream>>>(gcnt, G, goff, (int*)nullptr);
    fill_csr<<<(E + tb - 1) / tb, tb, 0, stream>>>(src, dst, cursor, colsrc, E);

    const int gemm_blocks = (N + 63) / 64;
    const int agg_blocks  = (N + 3) / 4;

    // layer 1
    gemm_scale_h<<<gemm_blocks, 256, 0, stream>>>(x, W1, dv, hsA, N);
    agg_relu_h<<<agg_blocks, 256, 0, stream>>>((const __half2*)hsA, dv, b1, rowoff, colsrc, hB, N);
    // layer 2
    gemm_scale_h<<<gemm_blocks, 256, 0, stream>>>(hB, W2, dv, hsA, N);
    agg_relu_h<<<agg_blocks, 256, 0, stream>>>((const __half2*)hsA, dv, b2, rowoff, colsrc, hB, N);
    // layer 3 (shared weights W2/b2)
    gemm_scale_h<<<gemm_blocks, 256, 0, stream>>>(hB, W2, dv, hsA, N);
    agg_relu_h<<<agg_blocks, 256, 0, stream>>>((const __half2*)hsA, dv, b2, rowoff, colsrc, hB, N);

    pool_kernel<<<G, 128, 0, stream>>>(hB, goff, gfeat);
    mlp_kernel<<<G, 128, 0, stream>>>(gfeat, lw1, lb1, lw2, lb2, lw3, lb3, out);
}

// Round 3
// 370.432 us; speedup vs baseline: 1.7960x; 1.3769x over previous
//
#include <hip/hip_runtime.h>
#include <hip/hip_bf16.h>
#include <hip/hip_fp16.h>
#include <math.h>

// ---------------------------------------------------------------------------
// GCN: 3x gcn_conv(relu) -> tri-pool per graph -> MLP head -> sigmoid
// GEMMs on matrix cores (fp16 in, fp32 acc); intermediates fp16; aggregation
// via CSR (sorted by dst) built per call; pool offsets via binary search.
// ---------------------------------------------------------------------------

typedef _Float16 f16;
typedef _Float16 f16x2 __attribute__((ext_vector_type(2)));
typedef _Float16 f16x4 __attribute__((ext_vector_type(4)));
typedef _Float16 f16x8 __attribute__((ext_vector_type(8)));
typedef float f32x4 __attribute__((ext_vector_type(4)));

__global__ void count_kernel(const int* __restrict__ idx, int* __restrict__ cnt, int n) {
    int i = blockIdx.x * blockDim.x + threadIdx.x;
    if (i < n) atomicAdd(&cnt[idx[i]], 1);
}

__global__ void dinv_kernel(const int* __restrict__ deg, float* __restrict__ dv, int n) {
    int i = blockIdx.x * blockDim.x + threadIdx.x;
    if (i < n) dv[i] = 1.0f / sqrtf((float)deg[i] + 1.0f);
}

__device__ inline int wave_incl_scan(int v, int lane) {
    #pragma unroll
    for (int off = 1; off < 64; off <<= 1) {
        int nv = __shfl_up(v, off, 64);
        if (lane >= off) v += nv;
    }
    return v;
}

// Single-block exclusive scan of n ints; writes out[0..n] (out[n]=total).
// Duplicates result into out2 (cursor copy for CSR fill) if non-null.
__global__ void scan_excl(const int* __restrict__ in, int n,
                          int* __restrict__ out, int* __restrict__ out2) {
    __shared__ int wsum[16];
    __shared__ int carry_s;
    const int t = threadIdx.x;
    const int lane = t & 63;
    const int wid = t >> 6;
    if (t == 0) carry_s = 0;
    __syncthreads();
    const int CH = 4096;  // 1024 threads * 4 elems
    for (int base = 0; base < n; base += CH) {
        int i0 = base + t * 4;
        int v[4];
        #pragma unroll
        for (int j = 0; j < 4; ++j) v[j] = (i0 + j < n) ? in[i0 + j] : 0;
        int local = v[0] + v[1] + v[2] + v[3];
        int isc = wave_incl_scan(local, lane);
        if (lane == 63) wsum[wid] = isc;
        __syncthreads();
        int carry = carry_s;
        int wbase = 0;
        for (int w = 0; w < wid; ++w) wbase += wsum[w];
        int total = 0;
        for (int w = 0; w < 16; ++w) total += wsum[w];
        int run = carry + wbase + isc - local;  // exclusive prefix for v[0]
        #pragma unroll
        for (int j = 0; j < 4; ++j) {
            int i = i0 + j;
            if (i < n) {
                out[i] = run;
                if (out2) out2[i] = run;
            }
            run += v[j];
        }
        __syncthreads();
        if (t == 0) carry_s = carry + total;
        __syncthreads();
    }
    if (t == 0) out[n] = carry_s;
}

__global__ void fill_csr(const int* __restrict__ src, const int* __restrict__ dst,
                         int* __restrict__ cursor, int* __restrict__ colsrc, int E) {
    int e = blockIdx.x * blockDim.x + threadIdx.x;
    if (e < E) {
        int p = atomicAdd(&cursor[dst[e]], 1);
        colsrc[p] = src[e];
    }
}

// goff[g] = lower_bound(batch, g) over sorted batch; g in [0, G].
__global__ void graph_off(const int* __restrict__ batch, int N, int G,
                          int* __restrict__ goff) {
    int g = blockIdx.x * blockDim.x + threadIdx.x;
    if (g > G) return;
    int lo = 0, hi = N;
    while (lo < hi) {
        int mid = (lo + hi) >> 1;
        if (batch[mid] < g) lo = mid + 1; else hi = mid;
    }
    goff[g] = lo;
}

// x fp32 -> fp16 (n elements, n % 4 == 0)
__global__ void xcast(const float* __restrict__ x, f16* __restrict__ xh, int n4) {
    int i = blockIdx.x * blockDim.x + threadIdx.x;
    if (i < n4) {
        float4 v = ((const float4*)x)[i];
        f16x4 o;
        o[0] = (f16)v.x; o[1] = (f16)v.y; o[2] = (f16)v.z; o[3] = (f16)v.w;
        ((f16x4*)xh)[i] = o;
    }
}

// W (128x128 fp32, k-major) -> Wt (128x128 fp16, n-major: Wt[n][k] = W[k][n])
__global__ void wcast(const float* __restrict__ W1, const float* __restrict__ W2,
                      f16* __restrict__ Wt1, f16* __restrict__ Wt2) {
    int idx = blockIdx.x * blockDim.x + threadIdx.x;  // 0..16383
    int n = idx >> 7, k = idx & 127;
    Wt1[idx] = (f16)W1[k * 128 + n];
    Wt2[idx] = (f16)W2[k * 128 + n];
}

// out[m][:] = fp16((A[m][:] @ W) * dv[m]);  A: Mx128 fp16, Wt: n-major fp16.
// MFMA 16x16x32_f16, D[n][m] so lane's 4 acc regs are 4 consecutive n at one m.
// 4 waves/block: (wr: 16-row group) x (wc: 64-col half); 2 row steps -> 64 rows/block.
__global__ __launch_bounds__(256) void gemm_mfma(
    const f16* __restrict__ A, const f16* __restrict__ Wt,
    const float* __restrict__ dv, f16* __restrict__ out, int M) {
    const int lane = threadIdx.x & 63;
    const int w = threadIdx.x >> 6;
    const int wc = w & 1;
    const int wr = w >> 1;
    const int l15 = lane & 15;
    const int lg = lane >> 4;  // 0..3

    // Hoist Wt fragments (MFMA A-operand): A_op[n][k], n = l15, k = lg*8+j
    f16x8 wf[4][4];  // [nt][kb]
    #pragma unroll
    for (int nt = 0; nt < 4; ++nt) {
        const f16* wp = Wt + (size_t)(wc * 64 + nt * 16 + l15) * 128 + lg * 8;
        #pragma unroll
        for (int kb = 0; kb < 4; ++kb)
            wf[nt][kb] = *(const f16x8*)(wp + kb * 32);
    }

    #pragma unroll
    for (int step = 0; step < 2; ++step) {
        const int m = blockIdx.x * 64 + step * 32 + wr * 16 + l15;
        const int mc = min(m, M - 1);
        // X fragments (MFMA B-operand): B_op[k][m], k = lg*8+j, m = l15
        const f16* ap = A + (size_t)mc * 128 + lg * 8;
        f16x8 af[4];
        #pragma unroll
        for (int kb = 0; kb < 4; ++kb) af[kb] = *(const f16x8*)(ap + kb * 32);
        const float d = dv[mc];
        #pragma unroll
        for (int nt = 0; nt < 4; ++nt) {
            f32x4 acc = {0.f, 0.f, 0.f, 0.f};
            #pragma unroll
            for (int kb = 0; kb < 4; ++kb)
                acc = __builtin_amdgcn_mfma_f32_16x16x32_f16(wf[nt][kb], af[kb], acc, 0, 0, 0);
            if (m < M) {
                f16x4 o;
                o[0] = (f16)(acc[0] * d);
                o[1] = (f16)(acc[1] * d);
                o[2] = (f16)(acc[2] * d);
                o[3] = (f16)(acc[3] * d);
                *(f16x4*)(out + (size_t)m * 128 + wc * 64 + nt * 16 + lg * 4) = o;
            }
        }
    }
}

// One wave per node v; hs rows are 128 fp16:
//   out[v] = fp16(relu(b + dinv[v] * (hs[v] + sum_{e: dst=v} hs[src[e]])))
__global__ __launch_bounds__(256) void agg_relu_h(
    const f16x2* __restrict__ hs, const float* __restrict__ dv,
    const float* __restrict__ bias, const int* __restrict__ rowoff,
    const int* __restrict__ colsrc, f16* __restrict__ out, int n) {
    const int lane = threadIdx.x & 63;
    const int v = blockIdx.x * 4 + (threadIdx.x >> 6);
    if (v >= n) return;

    f16x2 h0 = hs[(size_t)v * 64 + lane];
    float accx = (float)h0[0], accy = (float)h0[1];
    const int e0 = rowoff[v], e1 = rowoff[v + 1];
    const int deg = e1 - e0;

    for (int base = 0; base < deg; base += 64) {
        const int cnt = min(64, deg - base);
        int myidx = (base + lane < deg) ? colsrc[e0 + base + lane] : 0;
        int j = 0;
        for (; j + 4 <= cnt; j += 4) {
            int s0 = __shfl(myidx, j);
            int s1 = __shfl(myidx, j + 1);
            int s2 = __shfl(myidx, j + 2);
            int s3 = __shfl(myidx, j + 3);
            f16x2 m0 = hs[(size_t)s0 * 64 + lane];
            f16x2 m1 = hs[(size_t)s1 * 64 + lane];
            f16x2 m2 = hs[(size_t)s2 * 64 + lane];
            f16x2 m3 = hs[(size_t)s3 * 64 + lane];
            accx += ((float)m0[0] + (float)m1[0]) + ((float)m2[0] + (float)m3[0]);
            accy += ((float)m0[1] + (float)m1[1]) + ((float)m2[1] + (float)m3[1]);
        }
        for (; j < cnt; ++j) {
            int s = __shfl(myidx, j);
            f16x2 mm = hs[(size_t)s * 64 + lane];
            accx += (float)mm[0];
            accy += (float)mm[1];
        }
    }

    float d = dv[v];
    float2 bb = *(const float2*)(bias + lane * 2);
    f16x2 o;
    o[0] = (f16)fmaxf(fmaf(d, accx, bb.x), 0.0f);
    o[1] = (f16)fmaxf(fmaf(d, accy, bb.y), 0.0f);
    *(f16x2*)(out + (size_t)v * 128 + lane * 2) = o;
}

// One block (128 threads) per graph; gfeat[g] = [pmean | pmax | psum] (fp32)
__global__ __launch_bounds__(128) void pool_kernel(
    const f16* __restrict__ h, const int* __restrict__ goff,
    float* __restrict__ gfeat) {
    const int g = blockIdx.x, f = threadIdx.x;
    const int s = goff[g], e = goff[g + 1];
    float sum = 0.0f, mx = 0.0f;  // h >= 0 post-relu; empty graph -> 0 matches ref
    for (int v = s; v < e; ++v) {
        float val = (float)h[(size_t)v * 128 + f];
        sum += val;
        mx = fmaxf(mx, val);
    }
    float cnt = (float)(e - s);
    float* gp = gfeat + (size_t)g * 384;
    gp[f]       = sum / fmaxf(cnt, 1.0f);
    gp[128 + f] = mx;
    gp[256 + f] = sum;
}

// One block (128 threads) per graph: relu(g@lw1+lb1) -> relu(@lw2+lb2) -> sigmoid(@lw3+lb3)
__global__ __launch_bounds__(128) void mlp_kernel(
    const float* __restrict__ gfeat,
    const float* __restrict__ lw1, const float* __restrict__ lb1,
    const float* __restrict__ lw2, const float* __restrict__ lb2,
    const float* __restrict__ lw3, const float* __restrict__ lb3,
    float* __restrict__ out) {
    __shared__ float gin[384];
    __shared__ float h1[384];
    __shared__ float red[128];
    const int g = blockIdx.x, t = threadIdx.x;

    for (int i = t; i < 384; i += 128) gin[i] = gfeat[(size_t)g * 384 + i];
    __syncthreads();

    for (int j = t; j < 384; j += 128) {
        float acc = lb1[j];
        for (int i = 0; i < 384; ++i) acc = fmaf(gin[i], lw1[(size_t)i * 384 + j], acc);
        h1[j] = fmaxf(acc, 0.0f);
    }
    __syncthreads();

    float acc2 = lb2[t];
    for (int i = 0; i < 384; ++i) acc2 = fmaf(h1[i], lw2[(size_t)i * 128 + t], acc2);
    float h2 = fmaxf(acc2, 0.0f);

    red[t] = h2 * lw3[t];
    __syncthreads();
    for (int s = 64; s > 0; s >>= 1) {
        if (t < s) red[t] += red[t + s];
        __syncthreads();
    }
    if (t == 0) {
        float z = red[0] + lb3[0];
        out[g] = 1.0f / (1.0f + expf(-z));
    }
}

extern "C" void kernel_launch(void* const* d_in, const int* in_sizes, int n_in,
                              void* d_out, int out_size, void* d_ws, size_t ws_size,
                              hipStream_t stream) {
    (void)n_in; (void)ws_size;
    const float* x     = (const float*)d_in[0];
    const int*   ei    = (const int*)d_in[1];
    const int*   batch = (const int*)d_in[2];
    const float* W1  = (const float*)d_in[3];
    const float* b1  = (const float*)d_in[4];
    const float* W2  = (const float*)d_in[5];
    const float* b2  = (const float*)d_in[6];
    const float* lw1 = (const float*)d_in[7];
    const float* lb1 = (const float*)d_in[8];
    const float* lw2 = (const float*)d_in[9];
    const float* lb2 = (const float*)d_in[10];
    const float* lw3 = (const float*)d_in[11];
    const float* lb3 = (const float*)d_in[12];
    float* out = (float*)d_out;

    const int N = in_sizes[2];      // 50000 nodes
    const int E = in_sizes[1] / 2;  // 800000 edges
    const int G = out_size;         // 512 graphs

    const int* src = ei;
    const int* dst = ei + E;

    size_t off = 0;
    auto alloc = [&](size_t bytes) -> void* {
        void* p = (char*)d_ws + off;
        off += (bytes + 255) & ~(size_t)255;
        return p;
    };
    f16*   hs     = (f16*)alloc((size_t)N * 128 * 2);   // gemm out (pre-scaled)
    f16*   hb     = (f16*)alloc((size_t)N * 128 * 2);   // agg out / next gemm in
    f16*   xh     = (f16*)alloc((size_t)N * 128 * 2);   // x cast to fp16
    f16*   Wt1    = (f16*)alloc((size_t)128 * 128 * 2);
    f16*   Wt2    = (f16*)alloc((size_t)128 * 128 * 2);
    float* dv     = (float*)alloc((size_t)N * 4);
    int*   deg    = (int*)alloc((size_t)N * 4);
    int*   rowoff = (int*)alloc((size_t)(N + 1) * 4);
    int*   cursor = (int*)alloc((size_t)N * 4);
    int*   colsrc = (int*)alloc((size_t)E * 4);
    int*   goff   = (int*)alloc((size_t)(G + 1) * 4);
    float* gfeat  = (float*)alloc((size_t)G * 384 * 4);

    hipMemsetAsync(deg, 0, (size_t)N * 4, stream);

    const int tb = 256;
    count_kernel<<<(E + tb - 1) / tb, tb, 0, stream>>>(dst, deg, E);
    dinv_kernel<<<(N + tb - 1) / tb, tb, 0, stream>>>(deg, dv, N);
    scan_excl<<<1, 1024, 0, stream>>>(deg, N, rowoff, cursor);
    fill_csr<<<(E + tb - 1) / tb, tb, 0, stream>>>(src, dst, cursor, colsrc, E);
    graph_off<<<(G + 1 + tb - 1) / tb, tb, 0, stream>>>(batch, N, G, goff);
    xcast<<<(N * 128 / 4 + tb - 1) / tb, tb, 0, stream>>>(x, xh, N * 128 / 4);
    wcast<<<64, 256, 0, stream>>>(W1, W2, Wt1, Wt2);

    const int gemm_blocks = (N + 63) / 64;
    const int agg_blocks  = (N + 3) / 4;

    // layer 1
    gemm_mfma<<<gemm_blocks, 256, 0, stream>>>(xh, Wt1, dv, hs, N);
    agg_relu_h<<<agg_blocks, 256, 0, stream>>>((const f16x2*)hs, dv, b1, rowoff, colsrc, hb, N);
    // layer 2
    gemm_mfma<<<gemm_blocks, 256, 0, stream>>>(hb, Wt2, dv, hs, N);
    agg_relu_h<<<agg_blocks, 256, 0, stream>>>((const f16x2*)hs, dv, b2, rowoff, colsrc, hb, N);
    // layer 3 (shared weights)
    gemm_mfma<<<gemm_blocks, 256, 0, stream>>>(hb, Wt2, dv, hs, N);
    agg_relu_h<<<agg_blocks, 256, 0, stream>>>((const f16x2*)hs, dv, b2, rowoff, colsrc, hb, N);

    pool_kernel<<<G, 128, 0, stream>>>(hb, goff, gfeat);
    mlp_kernel<<<G, 128, 0, stream>>>(gfeat, lw1, lb1, lw2, lb2, lw3, lb3, out);
}